// Round 1
// baseline (212.038 us; speedup 1.0000x reference)
//
#include <hip/hip_runtime.h>
#include <hip/hip_bf16.h>
#include <stdint.h>

typedef __bf16 bf16_t;
typedef __attribute__((ext_vector_type(8))) __bf16 bf16x8;
typedef __attribute__((ext_vector_type(4))) float f32x4;

// ---------------------------------------------------------------------------
// q8: exact re-implementation of reference to_float8.
// ---------------------------------------------------------------------------
__device__ __forceinline__ float q8(float v) {
    float a = __builtin_fabsf(v);
    float z = a + 1e-8f;
    int ei = ((__float_as_int(z) >> 23) & 0xff) - 127;
    ei = ei > 7 ? 7 : (ei < -7 ? -7 : ei);
    float p  = __int_as_float((ei + 127) << 23);
    float ip = __int_as_float((127 - ei) << 23);
    float m  = __builtin_fmaf(a, ip, -1.0f);
    float mq = __builtin_rintf(m * 8.0f) * 0.125f;
    float r  = (1.0f + mq) * p;
    return v < 0.0f ? -r : r;
}

__device__ __forceinline__ void gload_lds16(const bf16_t* g, bf16_t* l) {
    __builtin_amdgcn_global_load_lds(
        (__attribute__((address_space(1))) void*)(g),
        (__attribute__((address_space(3))) void*)(l), 16, 0, 0);
}

__device__ __forceinline__ bf16x8 cvt8(float4 a, float4 b) {
    bf16x8 o = { (bf16_t)a.x, (bf16_t)a.y, (bf16_t)a.z, (bf16_t)a.w,
                 (bf16_t)b.x, (bf16_t)b.y, (bf16_t)b.z, (bf16_t)b.w };
    return o;
}
__device__ __forceinline__ bf16x8 q8x8(float4 a, float4 b) {
    bf16x8 o = { (bf16_t)q8(a.x), (bf16_t)q8(a.y), (bf16_t)q8(a.z), (bf16_t)q8(a.w),
                 (bf16_t)q8(b.x), (bf16_t)q8(b.y), (bf16_t)q8(b.z), (bf16_t)q8(b.w) };
    return o;
}

// ---------------------------------------------------------------------------
// Fused pack kernel, 10240 blocks x 256 threads, 8 elems/thread, 16B stores.
//   [0,4096):      x rows   -> XU[:, 0:2048]      (bf16 cast)
//   [4096,6144):   u rows   -> XU[:, 2048:3072]   (2 rows/block)
//   [6144,8192):   A rows   -> AB[:, 0:2048]      (q8)
//   [8192,9216):   B rows   -> AB[:, 2048:3072]   (q8, 2 rows/block)
//   [9216,10240):  C rows   -> CQ                 (q8)
// ---------------------------------------------------------------------------
__global__ void pack_all(const float* __restrict__ x, const float* __restrict__ u,
                         const float* __restrict__ A, const float* __restrict__ B,
                         const float* __restrict__ C,
                         bf16_t* __restrict__ XU, bf16_t* __restrict__ AB,
                         bf16_t* __restrict__ CQ) {
    const unsigned bid = blockIdx.x;
    const int tid = threadIdx.x;
    if (bid < 4096u) {
        size_t r = bid; int col = tid * 8;
        float4 v0 = *(const float4*)&x[r * 2048 + col];
        float4 v1 = *(const float4*)&x[r * 2048 + col + 4];
        *(bf16x8*)&XU[r * 3072 + col] = cvt8(v0, v1);
    } else if (bid < 6144u) {
        unsigned b = bid - 4096u;
        size_t r = b * 2 + (tid >> 7); int col = (tid & 127) * 8;
        float4 v0 = *(const float4*)&u[r * 1024 + col];
        float4 v1 = *(const float4*)&u[r * 1024 + col + 4];
        *(bf16x8*)&XU[r * 3072 + 2048 + col] = cvt8(v0, v1);
    } else if (bid < 8192u) {
        size_t r = bid - 6144u; int col = tid * 8;
        float4 v0 = *(const float4*)&A[r * 2048 + col];
        float4 v1 = *(const float4*)&A[r * 2048 + col + 4];
        *(bf16x8*)&AB[r * 3072 + col] = q8x8(v0, v1);
    } else if (bid < 9216u) {
        unsigned b = bid - 8192u;
        size_t r = b * 2 + (tid >> 7); int col = (tid & 127) * 8;
        float4 v0 = *(const float4*)&B[r * 1024 + col];
        float4 v1 = *(const float4*)&B[r * 1024 + col + 4];
        *(bf16x8*)&AB[r * 3072 + 2048 + col] = q8x8(v0, v1);
    } else {
        size_t r = bid - 9216u; int col = tid * 8;
        float4 v0 = *(const float4*)&C[r * 2048 + col];
        float4 v1 = *(const float4*)&C[r * 2048 + col + 4];
        *(bf16x8*)&CQ[r * 2048 + col] = q8x8(v0, v1);
    }
}

// ---------------------------------------------------------------------------
// GEMM (B^T): outf[i,j] = q8( sum_k A[i,k]*B[j,k] ), f32 out, optional bf16.
// Round-8: counted-vmcnt double-buffered pipeline (T3-min + T4):
//  * 128x128 tile, BK=64, 512 threads (8 waves, 4x2), LDS = 2x(16+16)KB = 64KB
//    -> 2 blocks/CU unchanged.
//  * Raw s_barrier + `s_waitcnt vmcnt(4)`: the next tile's 4 global_load_lds
//    stay in flight ACROSS every barrier; vmcnt never drains to 0 in the main
//    loop (the __syncthreads() vmcnt(0) drain was the measured ~64% stall:
//    MfmaUtil 36% with zero conflicts and 23% HBM).
//  * stage(t+2) issued right after the post-compute barrier into the buffer
//    all waves just finished reading -> one full iteration of flight time.
//  * Hazards: reads of buf[t&1] at iter t guarded by vmcnt(4)+barrier (stage(t)
//    is older than the 4 allowed in-flight); ""::memory asm fences pin LDS
//    reads inside the barrier window. FP order identical to round-7 (same
//    ascending 32-wide K chunks), so output is bit-identical.
//  * gemm2 moves from BN=64 (8 MFMA/barrier, 309 TF) to this BN=128 template.
//  * XCD patch decode generalized: NBX x 32 grid, each XCD owns (NBX/2) x 8.
// ---------------------------------------------------------------------------
template<int NBX, bool DUAL>
__global__ __launch_bounds__(512, 4)
void gemm_q8_kernel(const bf16_t* __restrict__ A, const bf16_t* __restrict__ B,
                    float* __restrict__ outf, bf16_t* __restrict__ outb,
                    int M, int N, int K) {
    constexpr int BM = 128;
    constexpr int BN = 128;
    constexpr int BK = 64;                 // 8 chunks of 8 elems per row
    constexpr int PX = NBX / 2;            // XCD patch x-extent

    __shared__ alignas(16) bf16_t sA[2][BM * BK];
    __shared__ alignas(16) bf16_t sB[2][BN * BK];

    const int tid  = threadIdx.x;
    const int lane = tid & 63;
    const int wave = tid >> 6;       // 0..7
    const int wm   = wave & 3;       // 4 m-strips of 32 rows
    const int wn   = wave >> 2;      // 2 n-strips of 64 cols
    const int ln16 = lane & 15;
    const int quad = lane >> 4;

    // XCD patch swizzle: xcd = b&7 owns a PX x 8 patch of the NBX x 32 grid
    const int b   = blockIdx.x;
    const int xcd = b & 7;
    const int g   = b >> 3;
    const int bx  = (xcd & 1) * PX + (g % PX);
    const int by  = (xcd >> 1) * 8 + (g / PX);
    const int brow = by * BM;
    const int bcol = bx * BN;

    // staging pointers: LDS lane-linear slots, global chunk XOR-permuted
    const bf16_t* gA[2];
    const bf16_t* gB[2];
#pragma unroll
    for (int it = 0; it < 2; ++it) {
        int L = it * 512 + tid;
        int r = L >> 3, c = L & 7;
        gA[it] = A + (size_t)(brow + r) * K + (c ^ (r & 7)) * 8;
        gB[it] = B + (size_t)(bcol + r) * K + (c ^ (r & 7)) * 8;
    }

    // loop-invariant fragment LDS offsets (elements), s = K-substep (0..1)
    int a_off[2][2], b_off[4][2];
#pragma unroll
    for (int im = 0; im < 2; ++im) {
        int r = wm * 32 + im * 16 + ln16;
#pragma unroll
        for (int s = 0; s < 2; ++s) {
            int cg = s * 4 + quad;
            a_off[im][s] = (r * 8 + (cg ^ (r & 7))) * 8;
        }
    }
#pragma unroll
    for (int in = 0; in < 4; ++in) {
        int r = wn * 64 + in * 16 + ln16;
#pragma unroll
        for (int s = 0; s < 2; ++s) {
            int cg = s * 4 + quad;
            b_off[in][s] = (r * 8 + (cg ^ (r & 7))) * 8;
        }
    }

    f32x4 acc[2][4];
#pragma unroll
    for (int im = 0; im < 2; ++im)
#pragma unroll
        for (int in = 0; in < 4; ++in)
            acc[im][in] = (f32x4){0.f, 0.f, 0.f, 0.f};

    auto stage_tile = [&](int cur) {
#pragma unroll
        for (int it = 0; it < 2; ++it) {
            gload_lds16(gA[it], &sA[cur][(it * 512 + wave * 64) * 8]);
            gA[it] += BK;
        }
#pragma unroll
        for (int it = 0; it < 2; ++it) {
            gload_lds16(gB[it], &sB[cur][(it * 512 + wave * 64) * 8]);
            gB[it] += BK;
        }
    };

    auto compute_tile = [&](int cur) {
        const bf16_t* bA = sA[cur];
        const bf16_t* bB = sB[cur];
        __builtin_amdgcn_s_setprio(1);
#pragma unroll
        for (int s = 0; s < 2; ++s) {
            bf16x8 af[2], bfv[4];
#pragma unroll
            for (int im = 0; im < 2; ++im) af[im]  = *(const bf16x8*)(bA + a_off[im][s]);
#pragma unroll
            for (int in = 0; in < 4; ++in) bfv[in] = *(const bf16x8*)(bB + b_off[in][s]);
#pragma unroll
            for (int im = 0; im < 2; ++im)
#pragma unroll
                for (int in = 0; in < 4; ++in)
                    acc[im][in] = __builtin_amdgcn_mfma_f32_16x16x32_bf16(
                        af[im], bfv[in], acc[im][in], 0, 0, 0);
        }
        __builtin_amdgcn_s_setprio(0);
    };

    // prologue: two tiles in flight
    stage_tile(0);
    stage_tile(1);

    const int NT = K / BK;
    for (int t = 0; t < NT - 1; ++t) {
        const int cur = t & 1;
        // stage(t) done (only stage(t+1)'s 4 loads may remain in flight)
        asm volatile("s_waitcnt vmcnt(4)" ::: "memory");
        __builtin_amdgcn_s_barrier();          // all waves' stage(t) visible
        asm volatile("" ::: "memory");
        compute_tile(cur);
        asm volatile("" ::: "memory");
        __builtin_amdgcn_s_barrier();          // all waves done reading buf[cur]
        if (t + 2 < NT) stage_tile(cur);       // async refill, NOT drained
    }
    // peeled last tile: only stage(NT-1) outstanding -> full drain
    asm volatile("s_waitcnt vmcnt(0)" ::: "memory");
    __builtin_amdgcn_s_barrier();
    asm volatile("" ::: "memory");
    compute_tile((NT - 1) & 1);

    // epilogue: C/D layout col = lane&15, row = quad*4 + reg
    const int rbase = quad * 4;
#pragma unroll
    for (int im = 0; im < 2; ++im) {
#pragma unroll
        for (int in = 0; in < 4; ++in) {
            int gm = brow + wm * 32 + im * 16 + rbase;
            int gn = bcol + wn * 64 + in * 16 + ln16;
#pragma unroll
            for (int r = 0; r < 4; ++r) {
                float v = q8(acc[im][in][r]);
                outf[(size_t)(gm + r) * N + gn] = v;
                if (DUAL) outb[(size_t)(gm + r) * N + gn] = (bf16_t)v;
            }
        }
    }
}

// ---------------------------------------------------------------------------
extern "C" void kernel_launch(void* const* d_in, const int* in_sizes, int n_in,
                              void* d_out, int out_size, void* d_ws, size_t ws_size,
                              hipStream_t stream) {
    const float* x = (const float*)d_in[0];   // 4096 x 2048
    const float* u = (const float*)d_in[1];   // 4096 x 1024
    const float* A = (const float*)d_in[2];   // 2048 x 2048
    const float* B = (const float*)d_in[3];   // 2048 x 1024
    const float* C = (const float*)d_in[4];   // 1024 x 2048

    float* outf = (float*)d_out;
    float* xnf  = outf;                                 // 4096 x 2048 f32
    float* yf   = outf + (size_t)4096 * 2048;           // 4096 x 1024 f32

    uint8_t* ws = (uint8_t*)d_ws;
    bf16_t* XU = (bf16_t*)ws;                                            // 24 MB
    bf16_t* AB = (bf16_t*)(ws + (size_t)25165824);                       // 12 MB
    bf16_t* CQ = (bf16_t*)(ws + (size_t)25165824 + 12582912);            //  4 MB
    bf16_t* XN = (bf16_t*)(ws + (size_t)25165824 + 12582912 + 4194304);  // 16 MB

    pack_all<<<dim3(10240), 256, 0, stream>>>(x, u, A, B, C, XU, AB, CQ);

    // x_next = q8([x|u] @ [Aq|Bq]^T): M=4096 N=2048 K=3072; grid 16x32 = 512
    gemm_q8_kernel<16, true><<<dim3(512), 512, 0, stream>>>(
        XU, AB, xnf, XN, 4096, 2048, 3072);
    // y = q8(x_next @ Cq^T): M=4096 N=1024 K=2048; grid 8x32 = 256
    gemm_q8_kernel<8, false><<<dim3(256), 512, 0, stream>>>(
        XN, CQ, yf, nullptr, 4096, 1024, 2048);
}